// Round 13
// baseline (24.668 us; speedup 1.0000x reference)
//
#include <hip/hip_runtime.h>

#define NS 128
#define NX 512
#define NY 512
#define NT 2048
#define WIN 64          // per-sensor LDS window (pow2)
#define TI 16           // tile rows
#define TJ 16           // tile cols

// ===== NUMERICS CONTRACT (R2/R4/R10/R12 failed; R0/R3/R5-R9/R11 passed) ====
// floor(idx) must match the np reference everywhere; idx recipe, SCALAR ONLY:
//     d2   = dx*dx + dy*dy;                 // EXACT SOURCE TEXT, scalar
//     dist = sqrt_cr(d2);                   // proven bit-exact R7-R9,R11
//     idx  = dist * (1.0f/1500.0f) * (1.0f/4e-08f);  // two separate RN muls
// fract/trunc proven safe (R7+). FORBIDDEN list (each failed a round):
//   - folded scale inside sqrt (R2)
//   - raw 1-ulp v_sqrt for idx (R2)
//   - ANY float2/packed math on the idx path (R4 AND R12: identical absmax
//     4.494141 fingerprint -> packed ops do not preserve scalar RN bits)
//   - changing the d2 expression text (R4)
// Accumulation FORM is free but kept scalar (packed accum was co-present in
// both failures; not worth the risk for ~1 instr).
// Window coverage: ref pixel (8,8) of 16x16 tile; |p-ref| <= 11.32px *
// 78.28um = 885.6um -> |idx-idxc| <= 14.77; ws=(int)idxc-31 (raw v_sqrt
// base, +-0.2 slack) -> slot e = i0-ws in [15,47], e+1 <= 48 < 64. idx in
// [361,1306] -> ws >= 315, ws+63 <= 1369 < 2048: staging always in-bounds.

__device__ __forceinline__ float sqrt_cr(float x) {
    const float r0 = __builtin_amdgcn_sqrtf(x);               // <=1 ulp
    const float rd = __int_as_float(__float_as_int(r0) - 1);
    const float ru = __int_as_float(__float_as_int(r0) + 1);
    const float vd = fmaf(-rd, r0, x);
    const float vu = fmaf(-ru, r0, x);
    float r = (vd <= 0.0f) ? rd : r0;
    r = (vu > 0.0f) ? ru : r;
    return r;
}

__global__ __launch_bounds__(512, 8) void das_kernel(
        const float* __restrict__ x,        // (NS, NT)
        const float* __restrict__ sensors,  // (NS, 2)
        const float* __restrict__ grid,     // (P, 2)
        float* __restrict__ out) {          // (P,)
    __shared__ float win[NS * WIN];         // 32 KB sample windows
    __shared__ int ldsoff[NS];              // s*WIN - ws[s] (main-loop addr)
    __shared__ int gbase[NS];               // s*NT  + ws[s] (staging addr)
    __shared__ float part[2][512];

    const int tid = threadIdx.x;
    const int bi = blockIdx.x;              // 1024 blocks
    const int ti = bi >> 5;                 // 0..31
    const int tj = bi & 31;                 // 0..31

    // --- phase 1: per-sensor window base from tile reference pixel (8,8)
    if (tid < NS) {
        const float2 sv = reinterpret_cast<const float2*>(sensors)[tid];
        const float2 gc = reinterpret_cast<const float2*>(
            grid)[(ti * TI + 8) * NY + (tj * TJ + 8)];
        const float dx = gc.x - sv.x;
        const float dy = gc.y - sv.y;
        const float idxc = __builtin_amdgcn_sqrtf(dx * dx + dy * dy)
                           * (1.0f / 1500.0f) * (1.0f / 4e-08f);
        const int ws = (int)idxc - 31;      // window covers ws .. ws+63
        ldsoff[tid] = tid * WIN - ws;
        gbase[tid]  = tid * NT + ws;
    }
    __syncthreads();

    // --- phase 2: stage windows; each of 8 waves stages one sensor/round
    // (uniform row base, 64 consecutive floats = 256B coalesced)
    const int wv = tid >> 6;
    const int lane = tid & 63;
#pragma unroll
    for (int r = 0; r < NS / 8; ++r) {
        const int s = r * 8 + wv;
        win[s * WIN + lane] = x[gbase[s] + lane];
    }
    __syncthreads();

    // --- main loop: 2 pixels per lane (rows r and r+8), 32 sensors (4-way)
    const int quad = tid >> 7;              // sensor quarter
    const int pl = tid & 127;               // px0 in tile (rows 0..7)
    const int p0 = (ti * TI + (pl >> 4)) * NY + (tj * TJ + (pl & 15));
    const int p1 = p0 + 8 * NY;             // px1 = px0 + 8 rows

    const float2 g0 = reinterpret_cast<const float2*>(grid)[p0];
    const float2 g1 = reinterpret_cast<const float2*>(grid)[p1];

    const float inv_c = 1.0f / 1500.0f;
    const float inv_dt = 1.0f / 4e-08f;

    const int sbase = __builtin_amdgcn_readfirstlane(quad << 5);
    const float2* svp = reinterpret_cast<const float2*>(sensors) + sbase;

    float accA0 = 0.0f, accB0 = 0.0f;       // scalar chains only
    float accA1 = 0.0f, accB1 = 0.0f;
#pragma unroll
    for (int s4 = 0; s4 < 8; ++s4) {
        const int4 off4 = *reinterpret_cast<const int4*>(&ldsoff[sbase + s4 * 4]);
#pragma unroll
        for (int u = 0; u < 4; ++u) {
            const int s = s4 * 4 + u;
            const float2 sv = svp[s];                  // uniform -> s_load

            // FROZEN SCALAR DAG, pixel 0 (R8 text)
            const float dx0 = g0.x - sv.x;
            const float dy0 = g0.y - sv.y;
            const float dist0 = sqrt_cr(dx0 * dx0 + dy0 * dy0);
            const float idx0 = dist0 * inv_c * inv_dt;
            const int i00 = (int)idx0;                 // trunc == floor
            const float w00 = __builtin_amdgcn_fractf(idx0);

            // FROZEN SCALAR DAG, pixel 1
            const float dx1 = g1.x - sv.x;
            const float dy1 = g1.y - sv.y;
            const float dist1 = sqrt_cr(dx1 * dx1 + dy1 * dy1);
            const float idx1 = dist1 * inv_c * inv_dt;
            const int i10 = (int)idx1;
            const float w10 = __builtin_amdgcn_fractf(idx1);

            const int o = (u == 0) ? off4.x : (u == 1) ? off4.y
                        : (u == 2) ? off4.z : off4.w;  // static select
            const float* wp0 = &win[i00 + o];          // = &x[s*NT+i00] staged
            const float* wp1 = &win[i10 + o];
            const float y00 = wp0[0];                  // ds_read2_b32
            const float y01 = wp0[1];
            const float y10 = wp1[0];
            const float y11 = wp1[1];

            accA0 = fmaf(w00, y00 - y01, accA0);  accB0 += y01;
            accA1 = fmaf(w10, y10 - y11, accA1);  accB1 += y11;
        }
    }

    part[0][tid] = accA0 + accB0;           // px0 partial
    part[1][tid] = accA1 + accB1;           // px1 partial
    __syncthreads();
    if (tid < 256) {
        const int t = tid;                  // pixel in 16x16 tile
        const int c = t >> 7;               // 0: rows 0-7, 1: rows 8-15
        const int q = t & 127;
        const float v = part[c][q] + part[c][q + 128]
                      + part[c][q + 256] + part[c][q + 384];
        out[(ti * TI + (t >> 4)) * NY + (tj * TJ + (t & 15))] = v;
    }
}

extern "C" void kernel_launch(void* const* d_in, const int* in_sizes, int n_in,
                              void* d_out, int out_size, void* d_ws, size_t ws_size,
                              hipStream_t stream) {
    const float* x = (const float*)d_in[0];        // (1, NS, NT)
    const float* sensors = (const float*)d_in[1];  // (NS, 2)
    const float* grid = (const float*)d_in[2];     // (P, 2)
    float* out = (float*)d_out;                    // (1, NX, NY)

    const int nblocks = (NX / TI) * (NY / TJ);     // 1024 blocks, 512 threads
    das_kernel<<<nblocks, 512, 0, stream>>>(x, sensors, grid, out);
}

// Round 14
// 24.574 us; speedup vs baseline: 1.0038x; 1.0038x over previous
//
#include <hip/hip_runtime.h>

#define NS 128
#define NX 512
#define NY 512
#define NT 2048
#define WIN 64          // per-sensor LDS window (pow2)
#define TI 16           // tile rows
#define TJ 16           // tile cols

// ===== NUMERICS CONTRACT (R2/R4/R10/R12 failed; R0/R3/R5-R9/R11/R13 pass) ==
// floor(idx) must match the np reference everywhere; idx recipe, SCALAR ONLY:
//     d2   = dx*dx + dy*dy;                 // EXACT SOURCE TEXT, scalar
//     dist = sqrt_cr(d2);                   // proven bit-exact R7-R9,R11,R13
//     idx  = dist * (1.0f/1500.0f) * (1.0f/4e-08f);  // two separate RN muls
// fract/trunc proven safe (R7+). FORBIDDEN (each failed a round):
//   - folded scale inside sqrt (R2); raw 1-ulp v_sqrt for idx (R2)
//   - ANY float2/packed math on the idx path (R4+R12, identical 4.494141
//     fingerprint); changing the d2 expression text (R4)
// Sensor coords pass through LDS as PURE BIT COPIES (no arithmetic) — safe.
// Window coverage (WIN=64, ref px (8,8) of 16x16 tile): |Δ| <= 11.32px *
// 78.28um = 885.6um = 14.76 samples; ws=(int)idxc-31 -> slot e in [15,47],
// e+1 <= 48 < 64. idx in [361,1306] -> staging always in-bounds.
//
// R14 THEORY: R8/R11/R13 all plateau at 24.5us because the inner loop mixes
// SMEM s_loads (per-sensor state) with LDS reads on the shared lgkmcnt
// counter; SMEM returns out-of-order forcing lgkmcnt(0) drains. This kernel
// keeps the inner loop 100% LDS (in-order) via a packed float4 record.

__device__ __forceinline__ float sqrt_cr(float x) {
    const float r0 = __builtin_amdgcn_sqrtf(x);               // <=1 ulp
    const float rd = __int_as_float(__float_as_int(r0) - 1);
    const float ru = __int_as_float(__float_as_int(r0) + 1);
    const float vd = fmaf(-rd, r0, x);
    const float vu = fmaf(-ru, r0, x);
    float r = (vd <= 0.0f) ? rd : r0;
    r = (vu > 0.0f) ? ru : r;
    return r;
}

__global__ __launch_bounds__(512, 8) void das_kernel(
        const float* __restrict__ x,        // (NS, NT)
        const float* __restrict__ sensors,  // (NS, 2)
        const float* __restrict__ grid,     // (P, 2)
        float* __restrict__ out) {          // (P,)
    __shared__ float4 rec[NS];              // {sx, sy, elemoff bits, gbase bits}
    __shared__ float win[NS * WIN];         // 32 KB sample windows
    __shared__ float part[2][512];

    const int tid = threadIdx.x;
    const int bi = blockIdx.x;              // 1024 blocks
    const int ti = bi >> 5;                 // 0..31
    const int tj = bi & 31;                 // 0..31

    // --- phase 1: per-sensor record from tile reference pixel (8,8)
    if (tid < NS) {
        const float2 sv = reinterpret_cast<const float2*>(sensors)[tid];
        const float2 gc = reinterpret_cast<const float2*>(
            grid)[(ti * TI + 8) * NY + (tj * TJ + 8)];
        const float dx = gc.x - sv.x;
        const float dy = gc.y - sv.y;
        const float idxc = __builtin_amdgcn_sqrtf(dx * dx + dy * dy)
                           * (1.0f / 1500.0f) * (1.0f / 4e-08f);
        const int ws = (int)idxc - 31;      // window covers ws .. ws+63
        rec[tid] = make_float4(sv.x, sv.y,
                               __int_as_float(tid * WIN - ws),
                               __int_as_float(tid * NT + ws));
    }
    __syncthreads();

    // --- phase 2: stage windows; each of 8 waves stages one sensor/round
    const int wv = tid >> 6;
    const int lane = tid & 63;
#pragma unroll
    for (int r = 0; r < NS / 8; ++r) {
        const int s = r * 8 + wv;
        const int gb = __float_as_int(rec[s].w);   // uniform LDS broadcast
        win[s * WIN + lane] = x[gb + lane];        // 256B coalesced row copy
    }
    __syncthreads();

    // --- main loop: 2 pixels/lane (rows r, r+8), 32 sensors (4-way split)
    // 100% LDS in the loop body: ds_read_b128 (rec) + 2x ds_read2_b32 (win)
    const int quad = tid >> 7;              // sensor quarter
    const int pl = tid & 127;               // px0 in tile (rows 0..7)
    const int p0 = (ti * TI + (pl >> 4)) * NY + (tj * TJ + (pl & 15));
    const int p1 = p0 + 8 * NY;             // px1 = px0 + 8 rows

    const float2 g0 = reinterpret_cast<const float2*>(grid)[p0];
    const float2 g1 = reinterpret_cast<const float2*>(grid)[p1];

    const float inv_c = 1.0f / 1500.0f;
    const float inv_dt = 1.0f / 4e-08f;

    const int sbase = __builtin_amdgcn_readfirstlane(quad << 5);
    const float4* recp = rec + sbase;

    float accA0 = 0.0f, accB0 = 0.0f;       // scalar chains only
    float accA1 = 0.0f, accB1 = 0.0f;
#pragma unroll
    for (int s = 0; s < 32; ++s) {
        const float4 rc = recp[s];                 // ds_read_b128, uniform
        const float svx = rc.x;
        const float svy = rc.y;
        const int o = __float_as_int(rc.z);        // window element offset

        // FROZEN SCALAR DAG, pixel 0 (R13 text)
        const float dx0 = g0.x - svx;
        const float dy0 = g0.y - svy;
        const float dist0 = sqrt_cr(dx0 * dx0 + dy0 * dy0);
        const float idx0 = dist0 * inv_c * inv_dt;
        const int i00 = (int)idx0;                 // trunc == floor
        const float w00 = __builtin_amdgcn_fractf(idx0);

        // FROZEN SCALAR DAG, pixel 1
        const float dx1 = g1.x - svx;
        const float dy1 = g1.y - svy;
        const float dist1 = sqrt_cr(dx1 * dx1 + dy1 * dy1);
        const float idx1 = dist1 * inv_c * inv_dt;
        const int i10 = (int)idx1;
        const float w10 = __builtin_amdgcn_fractf(idx1);

        const float* wp0 = &win[i00 + o];          // = &x[s*NT+i00] staged
        const float* wp1 = &win[i10 + o];
        const float y00 = wp0[0];                  // ds_read2_b32
        const float y01 = wp0[1];
        const float y10 = wp1[0];
        const float y11 = wp1[1];

        accA0 = fmaf(w00, y00 - y01, accA0);  accB0 += y01;
        accA1 = fmaf(w10, y10 - y11, accA1);  accB1 += y11;
    }

    part[0][tid] = accA0 + accB0;           // px0 partial
    part[1][tid] = accA1 + accB1;           // px1 partial
    __syncthreads();
    if (tid < 256) {
        const int t = tid;                  // pixel in 16x16 tile
        const int c = t >> 7;               // 0: rows 0-7, 1: rows 8-15
        const int q = t & 127;
        const float v = part[c][q] + part[c][q + 128]
                      + part[c][q + 256] + part[c][q + 384];
        out[(ti * TI + (t >> 4)) * NY + (tj * TJ + (t & 15))] = v;
    }
}

extern "C" void kernel_launch(void* const* d_in, const int* in_sizes, int n_in,
                              void* d_out, int out_size, void* d_ws, size_t ws_size,
                              hipStream_t stream) {
    const float* x = (const float*)d_in[0];        // (1, NS, NT)
    const float* sensors = (const float*)d_in[1];  // (NS, 2)
    const float* grid = (const float*)d_in[2];     // (P, 2)
    float* out = (float*)d_out;                    // (1, NX, NY)

    const int nblocks = (NX / TI) * (NY / TJ);     // 1024 blocks, 512 threads
    das_kernel<<<nblocks, 512, 0, stream>>>(x, sensors, grid, out);
}